// Round 13
// baseline (1921.898 us; speedup 1.0000x reference)
//
#include <hip/hip_runtime.h>

// ---------------------------------------------------------------------------
// SemmaRelModel: two 6-layer NBFNet branches + MLP fusion.
// Round 13: fuse gather+update into one k_layer_all per layer.
//   - fp32 state updated IN PLACE (gather reads only the bf16 mirror of
//     other nodes; fp32 reads are own-row only -> no cross-block hazard).
//   - mirror ping-pongs (read layer i, write layer i+1).
//   - agg buffer eliminated (-77 MB/layer), half the per-layer launches.
//   - acc staged in LDS with XOR swizzle ((row&7)<<2 on word idx): float4
//     reads hit 8 banks 2-way (free), zero padding.
// ---------------------------------------------------------------------------

__device__ __forceinline__ float bf2f(unsigned short u) {
    return __uint_as_float(((unsigned)u) << 16);
}
__device__ __forceinline__ unsigned short f2bf(float f) {
    unsigned u = __float_as_uint(f);
    u += 0x7FFF + ((u >> 16) & 1);          // round-to-nearest-even
    return (unsigned short)(u >> 16);
}
#define PACK2(a, b) ((unsigned)f2bf(a) | ((unsigned)f2bf(b) << 16))
#define SWZ(r) (((r) & 7) << 2)

__device__ __forceinline__ float4 lnout(float4 A, float m, float inv,
                                        float4 xv, float4 gg, float4 bb) {
    float4 y;
    y.x = fmaxf((A.x - m) * inv * gg.x + bb.x, 0.f) + xv.x;
    y.y = fmaxf((A.y - m) * inv * gg.y + bb.y, 0.f) + xv.y;
    y.z = fmaxf((A.z - m) * inv * gg.z + bb.z, 0.f) + xv.z;
    y.w = fmaxf((A.w - m) * inv * gg.w + bb.w, 0.f) + xv.w;
    return y;
}

#define FMA4R(v, wbase, R0, R1, R2, R3) do {                                  \
    const float4* _w = (const float4*)(wbase); float4 _t;                     \
    _t=_w[0]; R0.x=fmaf(v,_t.x,R0.x); R0.y=fmaf(v,_t.y,R0.y); R0.z=fmaf(v,_t.z,R0.z); R0.w=fmaf(v,_t.w,R0.w); \
    _t=_w[1]; R1.x=fmaf(v,_t.x,R1.x); R1.y=fmaf(v,_t.y,R1.y); R1.z=fmaf(v,_t.z,R1.z); R1.w=fmaf(v,_t.w,R1.w); \
    _t=_w[2]; R2.x=fmaf(v,_t.x,R2.x); R2.y=fmaf(v,_t.y,R2.y); R2.z=fmaf(v,_t.z,R2.z); R2.w=fmaf(v,_t.w,R2.w); \
    _t=_w[3]; R3.x=fmaf(v,_t.x,R3.x); R3.y=fmaf(v,_t.y,R3.y); R3.z=fmaf(v,_t.z,R3.z); R3.w=fmaf(v,_t.w,R3.w); \
} while (0)

#define FMA4R2(v0, v1, wbase, P0,P1,P2,P3, Q0,Q1,Q2,Q3) do {                  \
    const float4* _w = (const float4*)(wbase); float4 _t;                     \
    _t=_w[0];                                                                 \
    P0.x=fmaf(v0,_t.x,P0.x); P0.y=fmaf(v0,_t.y,P0.y); P0.z=fmaf(v0,_t.z,P0.z); P0.w=fmaf(v0,_t.w,P0.w); \
    Q0.x=fmaf(v1,_t.x,Q0.x); Q0.y=fmaf(v1,_t.y,Q0.y); Q0.z=fmaf(v1,_t.z,Q0.z); Q0.w=fmaf(v1,_t.w,Q0.w); \
    _t=_w[1];                                                                 \
    P1.x=fmaf(v0,_t.x,P1.x); P1.y=fmaf(v0,_t.y,P1.y); P1.z=fmaf(v0,_t.z,P1.z); P1.w=fmaf(v0,_t.w,P1.w); \
    Q1.x=fmaf(v1,_t.x,Q1.x); Q1.y=fmaf(v1,_t.y,Q1.y); Q1.z=fmaf(v1,_t.z,Q1.z); Q1.w=fmaf(v1,_t.w,Q1.w); \
    _t=_w[2];                                                                 \
    P2.x=fmaf(v0,_t.x,P2.x); P2.y=fmaf(v0,_t.y,P2.y); P2.z=fmaf(v0,_t.z,P2.z); P2.w=fmaf(v0,_t.w,P2.w); \
    Q2.x=fmaf(v1,_t.x,Q2.x); Q2.y=fmaf(v1,_t.y,Q2.y); Q2.z=fmaf(v1,_t.z,Q2.z); Q2.w=fmaf(v1,_t.w,Q2.w); \
    _t=_w[3];                                                                 \
    P3.x=fmaf(v0,_t.x,P3.x); P3.y=fmaf(v0,_t.y,P3.y); P3.z=fmaf(v0,_t.z,P3.z); P3.w=fmaf(v0,_t.w,P3.w); \
    Q3.x=fmaf(v1,_t.x,Q3.x); Q3.y=fmaf(v1,_t.y,Q3.y); Q3.z=fmaf(v1,_t.z,Q3.z); Q3.w=fmaf(v1,_t.w,Q3.w); \
} while (0)

#define SUM4(Ai) ((Ai.x + Ai.y) + (Ai.z + Ai.w))
#define VAR4M(Ai, mm, vv) do { float _c;                                      \
    _c = Ai.x - mm; vv = fmaf(_c, _c, vv); _c = Ai.y - mm; vv = fmaf(_c, _c, vv); \
    _c = Ai.z - mm; vv = fmaf(_c, _c, vv); _c = Ai.w - mm; vv = fmaf(_c, _c, vv); \
} while (0)

#define RSEL(ty) (((ty) < 2) ? ((ty) == 0 ? r0 : r1) : ((ty) == 2 ? r2 : r3))

__global__ __launch_bounds__(256) void k_init_onehot(
    float* __restrict__ x, unsigned* __restrict__ xmir,
    const int* __restrict__ h_index, int N, int total, int b2)
{
    int idx = blockIdx.x * 256 + threadIdx.x;
    if (idx >= total) return;
    int row = idx >> 6;
    int b = row / N;
    int n = row - b * N;
    x[idx] = (n == h_index[b]) ? 1.0f : 0.0f;
    if (b2 && idx < N * 64) {
        int nn = idx >> 6;
        unsigned w = ((nn == h_index[0]) ? 0x3F80u : 0u)
                   | (((nn == h_index[1]) ? 0x3F80u : 0u) << 16);
        xmir[idx] = w;
    }
}

__global__ __launch_bounds__(256) void k_cast_init(
    const float* __restrict__ init, float* __restrict__ x,
    unsigned short* __restrict__ xbf, int total)
{
    int idx = blockIdx.x * 256 + threadIdx.x;
    if (idx >= total) return;
    float f = init[idx];
    x[idx] = f;
    xbf[idx] = f2bf(f);
}

// ---- CSR build (both graphs per launch) ----
__global__ __launch_bounds__(256) void k_hist_all(
    const int* __restrict__ dst_s, const int* __restrict__ dst_t,
    int* __restrict__ cnt_s, int* __restrict__ cnt_t, int E, int ET)
{
    int i = blockIdx.x * 256 + threadIdx.x;
    if (i < E) atomicAdd(&cnt_s[dst_s[i]], 1);
    else if (i < E + ET) atomicAdd(&cnt_t[dst_t[i - E]], 1);
}

__global__ __launch_bounds__(1024) void k_scan_blk2(
    const int* __restrict__ cnt_s, int* __restrict__ off_s, int* __restrict__ bsum_s,
    const int* __restrict__ cnt_t, int* __restrict__ off_t, int* __restrict__ bsum_t,
    int n, int nb)
{
    bool tpath = blockIdx.x >= nb;
    int lb = tpath ? blockIdx.x - nb : blockIdx.x;
    const int* cnt = tpath ? cnt_t : cnt_s;
    int* off = tpath ? off_t : off_s;
    int* bsum = tpath ? bsum_t : bsum_s;

    __shared__ int wsum[16], wpre[16], tot;
    int tid = threadIdx.x, lane = tid & 63, w = tid >> 6;
    int i = lb * 1024 + tid;
    int v = (i < n) ? cnt[i] : 0;
    int s = v;
    #pragma unroll
    for (int d = 1; d < 64; d <<= 1) {
        int t = __shfl_up(s, d);
        if (lane >= d) s += t;
    }
    if (lane == 63) wsum[w] = s;
    __syncthreads();
    if (w == 0 && lane < 16) {
        int ws = wsum[lane];
        int p = ws;
        #pragma unroll
        for (int d = 1; d < 16; d <<= 1) {
            int t = __shfl_up(p, d);
            if (lane >= d) p += t;
        }
        wpre[lane] = p - ws;
        if (lane == 15) tot = p;
    }
    __syncthreads();
    if (i < n) off[i + 1] = wpre[w] + s;
    if (tid == 0) {
        bsum[lb] = tot;
        if (lb == 0) off[0] = 0;
    }
}

__global__ __launch_bounds__(1024) void k_scan_top2(
    int* __restrict__ bsum_s, int* __restrict__ bsum_t, int nb)
{
    int* bsum = (blockIdx.x == 0) ? bsum_s : bsum_t;
    __shared__ int wsum[16], wpre[16];
    int tid = threadIdx.x, lane = tid & 63, w = tid >> 6;
    int v = (tid < nb) ? bsum[tid] : 0;
    int s = v;
    #pragma unroll
    for (int d = 1; d < 64; d <<= 1) {
        int t = __shfl_up(s, d);
        if (lane >= d) s += t;
    }
    if (lane == 63) wsum[w] = s;
    __syncthreads();
    if (w == 0 && lane < 16) {
        int ws = wsum[lane];
        int p = ws;
        #pragma unroll
        for (int d = 1; d < 16; d <<= 1) {
            int t = __shfl_up(p, d);
            if (lane >= d) p += t;
        }
        wpre[lane] = p - ws;
    }
    __syncthreads();
    if (tid < nb) bsum[tid] = wpre[w] + s - v;
}

__global__ __launch_bounds__(1024) void k_scan_add2(
    const int* __restrict__ bsum_s, int* __restrict__ off_s,
    const int* __restrict__ bsum_t, int* __restrict__ off_t, int n, int nb)
{
    bool tpath = blockIdx.x >= nb;
    int lb = tpath ? blockIdx.x - nb : blockIdx.x;
    int i = lb * 1024 + threadIdx.x;
    if (i < n) (tpath ? off_t : off_s)[i + 1] += (tpath ? bsum_t : bsum_s)[lb];
}

__global__ __launch_bounds__(256) void k_fill_all(
    const int* __restrict__ src_s, const int* __restrict__ dst_s,
    const int* __restrict__ etype,
    const int* __restrict__ off_s, int* __restrict__ cnt_s, int* __restrict__ pk_s,
    const int* __restrict__ src_t, const int* __restrict__ dst_t,
    const int* __restrict__ off_t, int* __restrict__ cnt_t, int* __restrict__ pk_t,
    int E, int ET)
{
    int i = blockIdx.x * 256 + threadIdx.x;
    if (i < E) {
        int d = dst_s[i];
        int pos = off_s[d] + atomicSub(&cnt_s[d], 1) - 1;
        pk_s[pos] = src_s[i] | (etype[i] << 27);
    } else if (i < E + ET) {
        int e = i - E;
        int d = dst_t[e];
        int pos = off_t[d] + atomicSub(&cnt_t[d], 1) - 1;
        pk_t[pos] = src_t[e];
    }
}

// ---- fused layer: gather (-> LDS) + dense update, struct + text blocks ----
__global__ __launch_bounds__(256) void k_layer_all(
    const unsigned* __restrict__ mi_s, unsigned* __restrict__ mo_s,
    float* __restrict__ xs,
    const int* __restrict__ offs, const int* __restrict__ pks,
    const float* __restrict__ rels, const int* __restrict__ hidx,
    const float* __restrict__ Ws, const float* __restrict__ bs_,
    const float* __restrict__ gs, const float* __restrict__ betas,
    const unsigned short* __restrict__ mi_t, unsigned short* __restrict__ mo_t,
    float* __restrict__ xt,
    const int* __restrict__ offt, const int* __restrict__ pkt,
    const float* __restrict__ relt, const float* __restrict__ tinit,
    const float* __restrict__ Wt, const float* __restrict__ bt_,
    const float* __restrict__ gt_, const float* __restrict__ betat,
    int N, int sblocks, int tblocks)
{
    __shared__ float Wl[128 * 64];
    __shared__ float accL[128 * 64];        // XOR-swizzled rows
    __shared__ float bl[64], gl[64], bel[64];

    int tid = threadIdx.x, lane = tid & 63, w = tid >> 6;
    bool isStruct; int lb;
    if (sblocks == tblocks) { isStruct = !(blockIdx.x & 1); lb = blockIdx.x >> 1; }
    else if ((int)blockIdx.x < sblocks) { isStruct = true; lb = blockIdx.x; }
    else { isStruct = false; lb = blockIdx.x - sblocks; }

    {
        const float* W = isStruct ? Ws : Wt;
        const float4* W4 = (const float4*)W;
        float4* Wl4 = (float4*)Wl;
        #pragma unroll
        for (int i = 0; i < 8; ++i) Wl4[tid + i * 256] = W4[tid + i * 256];
        if (tid < 64) {
            bl[tid]  = (isStruct ? bs_ : bt_)[tid];
            gl[tid]  = (isStruct ? gs : gt_)[tid];
            bel[tid] = (isStruct ? betas : betat)[tid];
        }
    }
    int nodeBase = lb * 64;

    if (isStruct) {
        // ---- phase 1: gather 16 nodes per wave, both batches ----
        float r0 = rels[lane], r1 = rels[64 + lane];
        float r2 = rels[128 + lane], r3 = rels[192 + lane];
        int h0 = hidx[0], h1i = hidx[1];
        for (int j = 0; j < 16; ++j) {
            int n = nodeBase + w * 16 + j;
            if (n >= N) break;
            float acc0 = (n == h0) ? 1.0f : 0.0f;
            float acc1 = (n == h1i) ? 1.0f : 0.0f;
            int p0 = __builtin_amdgcn_readfirstlane(offs[n]);
            int p1 = __builtin_amdgcn_readfirstlane(offs[n + 1]);
            for (int p = p0; p < p1; p += 64) {
                int myPk = (p + lane < p1) ? pks[p + lane] : 0;
                int cnt = min(p1 - p, 64);
                int i = 0;
                for (; i + 8 <= cnt; i += 8) {
                    int k0 = __shfl(myPk, i + 0), k1 = __shfl(myPk, i + 1);
                    int k2 = __shfl(myPk, i + 2), k3 = __shfl(myPk, i + 3);
                    int k4 = __shfl(myPk, i + 4), k5 = __shfl(myPk, i + 5);
                    int k6 = __shfl(myPk, i + 6), k7 = __shfl(myPk, i + 7);
                    unsigned w0 = mi_s[(size_t)(k0 & 0x03FFFFFF) * 64 + lane];
                    unsigned w1 = mi_s[(size_t)(k1 & 0x03FFFFFF) * 64 + lane];
                    unsigned w2 = mi_s[(size_t)(k2 & 0x03FFFFFF) * 64 + lane];
                    unsigned w3 = mi_s[(size_t)(k3 & 0x03FFFFFF) * 64 + lane];
                    unsigned w4 = mi_s[(size_t)(k4 & 0x03FFFFFF) * 64 + lane];
                    unsigned w5 = mi_s[(size_t)(k5 & 0x03FFFFFF) * 64 + lane];
                    unsigned w6 = mi_s[(size_t)(k6 & 0x03FFFFFF) * 64 + lane];
                    unsigned w7 = mi_s[(size_t)(k7 & 0x03FFFFFF) * 64 + lane];
                    int t0 = k0 >> 27, t1 = k1 >> 27, t2 = k2 >> 27, t3 = k3 >> 27;
                    int t4 = k4 >> 27, t5 = k5 >> 27, t6 = k6 >> 27, t7 = k7 >> 27;
                    float ra = RSEL(t0), rb = RSEL(t1), rc = RSEL(t2), rd = RSEL(t3);
                    float re = RSEL(t4), rf = RSEL(t5), rg = RSEL(t6), rh = RSEL(t7);
                    acc0 = fmaf(bf2f((unsigned short)w0), ra, acc0);
                    acc1 = fmaf(bf2f((unsigned short)(w0 >> 16)), ra, acc1);
                    acc0 = fmaf(bf2f((unsigned short)w1), rb, acc0);
                    acc1 = fmaf(bf2f((unsigned short)(w1 >> 16)), rb, acc1);
                    acc0 = fmaf(bf2f((unsigned short)w2), rc, acc0);
                    acc1 = fmaf(bf2f((unsigned short)(w2 >> 16)), rc, acc1);
                    acc0 = fmaf(bf2f((unsigned short)w3), rd, acc0);
                    acc1 = fmaf(bf2f((unsigned short)(w3 >> 16)), rd, acc1);
                    acc0 = fmaf(bf2f((unsigned short)w4), re, acc0);
                    acc1 = fmaf(bf2f((unsigned short)(w4 >> 16)), re, acc1);
                    acc0 = fmaf(bf2f((unsigned short)w5), rf, acc0);
                    acc1 = fmaf(bf2f((unsigned short)(w5 >> 16)), rf, acc1);
                    acc0 = fmaf(bf2f((unsigned short)w6), rg, acc0);
                    acc1 = fmaf(bf2f((unsigned short)(w6 >> 16)), rg, acc1);
                    acc0 = fmaf(bf2f((unsigned short)w7), rh, acc0);
                    acc1 = fmaf(bf2f((unsigned short)(w7 >> 16)), rh, acc1);
                }
                for (; i < cnt; ++i) {
                    int pk = __shfl(myPk, i);
                    int s = pk & 0x03FFFFFF, ty = pk >> 27;
                    float r = RSEL(ty);
                    unsigned ww = mi_s[(size_t)s * 64 + lane];
                    acc0 = fmaf(bf2f((unsigned short)ww), r, acc0);
                    acc1 = fmaf(bf2f((unsigned short)(ww >> 16)), r, acc1);
                }
            }
            int r0loc = w * 16 + j, r1loc = 64 + r0loc;
            accL[r0loc * 64 + (lane ^ SWZ(r0loc))] = acc0;
            accL[r1loc * 64 + (lane ^ SWZ(r1loc))] = acc1;
        }
        __syncthreads();

        // ---- phase 2: GEMV + LN + residual for rows (n, N+n) ----
        int pair = tid >> 2, q = tid & 3, jc = q * 16;
        int n = nodeBase + pair;
        if (n >= N) return;
        const float* xr0 = xs + (size_t)n * 64;
        const float* xr1 = xs + ((size_t)N + n) * 64;
        const float* aL0 = accL + pair * 64;
        const float* aL1 = accL + (64 + pair) * 64;
        int swz = SWZ(pair);                 // (64+pair)&7 == pair&7

        const float4* bj = (const float4*)(bl + jc);
        float4 A0 = bj[0], A1 = bj[1], A2 = bj[2], A3 = bj[3];
        float4 B0 = bj[0], B1 = bj[1], B2 = bj[2], B3 = bj[3];

        #pragma unroll
        for (int kb = 0; kb < 64; kb += 4) {
            float4 i0 = *(const float4*)(xr0 + kb);
            float4 i1 = *(const float4*)(xr1 + kb);
            FMA4R2(i0.x, i1.x, Wl + (kb + 0) * 64 + jc, A0,A1,A2,A3, B0,B1,B2,B3);
            FMA4R2(i0.y, i1.y, Wl + (kb + 1) * 64 + jc, A0,A1,A2,A3, B0,B1,B2,B3);
            FMA4R2(i0.z, i1.z, Wl + (kb + 2) * 64 + jc, A0,A1,A2,A3, B0,B1,B2,B3);
            FMA4R2(i0.w, i1.w, Wl + (kb + 3) * 64 + jc, A0,A1,A2,A3, B0,B1,B2,B3);
        }
        #pragma unroll
        for (int kb = 0; kb < 64; kb += 4) {
            float4 i0 = *(const float4*)(aL0 + (kb ^ swz));
            float4 i1 = *(const float4*)(aL1 + (kb ^ swz));
            FMA4R2(i0.x, i1.x, Wl + (64 + kb + 0) * 64 + jc, A0,A1,A2,A3, B0,B1,B2,B3);
            FMA4R2(i0.y, i1.y, Wl + (64 + kb + 1) * 64 + jc, A0,A1,A2,A3, B0,B1,B2,B3);
            FMA4R2(i0.z, i1.z, Wl + (64 + kb + 2) * 64 + jc, A0,A1,A2,A3, B0,B1,B2,B3);
            FMA4R2(i0.w, i1.w, Wl + (64 + kb + 3) * 64 + jc, A0,A1,A2,A3, B0,B1,B2,B3);
        }

        float ls0 = SUM4(A0) + SUM4(A1) + SUM4(A2) + SUM4(A3);
        float ls1 = SUM4(B0) + SUM4(B1) + SUM4(B2) + SUM4(B3);
        ls0 += __shfl_xor(ls0, 1); ls0 += __shfl_xor(ls0, 2);
        ls1 += __shfl_xor(ls1, 1); ls1 += __shfl_xor(ls1, 2);
        float m0 = ls0 * (1.0f / 64.0f), m1 = ls1 * (1.0f / 64.0f);
        float v0 = 0.f, v1 = 0.f;
        VAR4M(A0, m0, v0); VAR4M(A1, m0, v0); VAR4M(A2, m0, v0); VAR4M(A3, m0, v0);
        VAR4M(B0, m1, v1); VAR4M(B1, m1, v1); VAR4M(B2, m1, v1); VAR4M(B3, m1, v1);
        v0 += __shfl_xor(v0, 1); v0 += __shfl_xor(v0, 2);
        v1 += __shfl_xor(v1, 1); v1 += __shfl_xor(v1, 2);
        float inv0 = rsqrtf(v0 * (1.0f / 64.0f) + 1e-5f);
        float inv1 = rsqrtf(v1 * (1.0f / 64.0f) + 1e-5f);

        const float4* gg4 = (const float4*)(gl + jc);
        const float4* bb4 = (const float4*)(bel + jc);
        float4 ya0 = lnout(A0, m0, inv0, ((const float4*)(xr0 + jc))[0], gg4[0], bb4[0]);
        float4 ya1 = lnout(A1, m0, inv0, ((const float4*)(xr0 + jc))[1], gg4[1], bb4[1]);
        float4 ya2 = lnout(A2, m0, inv0, ((const float4*)(xr0 + jc))[2], gg4[2], bb4[2]);
        float4 ya3 = lnout(A3, m0, inv0, ((const float4*)(xr0 + jc))[3], gg4[3], bb4[3]);
        float4 yb0 = lnout(B0, m1, inv1, ((const float4*)(xr1 + jc))[0], gg4[0], bb4[0]);
        float4 yb1 = lnout(B1, m1, inv1, ((const float4*)(xr1 + jc))[1], gg4[1], bb4[1]);
        float4 yb2 = lnout(B2, m1, inv1, ((const float4*)(xr1 + jc))[2], gg4[2], bb4[2]);
        float4 yb3 = lnout(B3, m1, inv1, ((const float4*)(xr1 + jc))[3], gg4[3], bb4[3]);

        float4* xw0 = (float4*)(xs + (size_t)n * 64 + jc);
        xw0[0] = ya0; xw0[1] = ya1; xw0[2] = ya2; xw0[3] = ya3;
        float4* xw1 = (float4*)(xs + ((size_t)N + n) * 64 + jc);
        xw1[0] = yb0; xw1[1] = yb1; xw1[2] = yb2; xw1[3] = yb3;

        uint4* mw = (uint4*)(mo_s + (size_t)n * 64 + jc);
        mw[0] = make_uint4(PACK2(ya0.x, yb0.x), PACK2(ya0.y, yb0.y),
                           PACK2(ya0.z, yb0.z), PACK2(ya0.w, yb0.w));
        mw[1] = make_uint4(PACK2(ya1.x, yb1.x), PACK2(ya1.y, yb1.y),
                           PACK2(ya1.z, yb1.z), PACK2(ya1.w, yb1.w));
        mw[2] = make_uint4(PACK2(ya2.x, yb2.x), PACK2(ya2.y, yb2.y),
                           PACK2(ya2.z, yb2.z), PACK2(ya2.w, yb2.w));
        mw[3] = make_uint4(PACK2(ya3.x, yb3.x), PACK2(ya3.y, yb3.y),
                           PACK2(ya3.z, yb3.z), PACK2(ya3.w, yb3.w));
    } else {
        // ---- text: phase 1 gather ----
        float r = relt[lane];
        for (int j = 0; j < 16; ++j) {
            int n = nodeBase + w * 16 + j;
            if (n >= N) break;
            float acc = tinit[(size_t)n * 64 + lane];
            float acc2 = 0.f;
            int p0 = __builtin_amdgcn_readfirstlane(offt[n]);
            int p1 = __builtin_amdgcn_readfirstlane(offt[n + 1]);
            for (int p = p0; p < p1; p += 64) {
                int myPk = (p + lane < p1) ? pkt[p + lane] : 0;
                int cnt = min(p1 - p, 64);
                int i = 0;
                for (; i + 8 <= cnt; i += 8) {
                    int s0 = __shfl(myPk, i + 0), s1 = __shfl(myPk, i + 1);
                    int s2 = __shfl(myPk, i + 2), s3 = __shfl(myPk, i + 3);
                    int s4 = __shfl(myPk, i + 4), s5 = __shfl(myPk, i + 5);
                    int s6 = __shfl(myPk, i + 6), s7 = __shfl(myPk, i + 7);
                    float a = bf2f(mi_t[(size_t)s0 * 64 + lane]), b = bf2f(mi_t[(size_t)s1 * 64 + lane]);
                    float c = bf2f(mi_t[(size_t)s2 * 64 + lane]), d = bf2f(mi_t[(size_t)s3 * 64 + lane]);
                    float e = bf2f(mi_t[(size_t)s4 * 64 + lane]), f = bf2f(mi_t[(size_t)s5 * 64 + lane]);
                    float g = bf2f(mi_t[(size_t)s6 * 64 + lane]), h = bf2f(mi_t[(size_t)s7 * 64 + lane]);
                    acc = fmaf(a, r, acc);  acc2 = fmaf(b, r, acc2);
                    acc = fmaf(c, r, acc);  acc2 = fmaf(d, r, acc2);
                    acc = fmaf(e, r, acc);  acc2 = fmaf(f, r, acc2);
                    acc = fmaf(g, r, acc);  acc2 = fmaf(h, r, acc2);
                }
                for (; i < cnt; ++i) {
                    int s = __shfl(myPk, i);
                    acc = fmaf(bf2f(mi_t[(size_t)s * 64 + lane]), r, acc);
                }
            }
            int rl = w * 16 + j;
            accL[rl * 64 + (lane ^ SWZ(rl))] = acc + acc2;
        }
        __syncthreads();

        // ---- text: phase 2 GEMV (single row) ----
        int pair = tid >> 2, q = tid & 3, jc = q * 16;
        int n = nodeBase + pair;
        if (n >= N) return;
        const float* xr = xt + (size_t)n * 64;
        const float* aL = accL + pair * 64;
        int swz = SWZ(pair);

        const float4* bj = (const float4*)(bl + jc);
        float4 A0 = bj[0], A1 = bj[1], A2 = bj[2], A3 = bj[3];
        #pragma unroll
        for (int kb = 0; kb < 64; kb += 4) {
            float4 iv = *(const float4*)(xr + kb);
            FMA4R(iv.x, Wl + (kb + 0) * 64 + jc, A0, A1, A2, A3);
            FMA4R(iv.y, Wl + (kb + 1) * 64 + jc, A0, A1, A2, A3);
            FMA4R(iv.z, Wl + (kb + 2) * 64 + jc, A0, A1, A2, A3);
            FMA4R(iv.w, Wl + (kb + 3) * 64 + jc, A0, A1, A2, A3);
        }
        #pragma unroll
        for (int kb = 0; kb < 64; kb += 4) {
            float4 iv = *(const float4*)(aL + (kb ^ swz));
            FMA4R(iv.x, Wl + (64 + kb + 0) * 64 + jc, A0, A1, A2, A3);
            FMA4R(iv.y, Wl + (64 + kb + 1) * 64 + jc, A0, A1, A2, A3);
            FMA4R(iv.z, Wl + (64 + kb + 2) * 64 + jc, A0, A1, A2, A3);
            FMA4R(iv.w, Wl + (64 + kb + 3) * 64 + jc, A0, A1, A2, A3);
        }
        float ls = SUM4(A0) + SUM4(A1) + SUM4(A2) + SUM4(A3);
        ls += __shfl_xor(ls, 1); ls += __shfl_xor(ls, 2);
        float m = ls * (1.0f / 64.0f);
        float vs = 0.f;
        VAR4M(A0, m, vs); VAR4M(A1, m, vs); VAR4M(A2, m, vs); VAR4M(A3, m, vs);
        vs += __shfl_xor(vs, 1); vs += __shfl_xor(vs, 2);
        float inv = rsqrtf(vs * (1.0f / 64.0f) + 1e-5f);

        const float4* gg4 = (const float4*)(gl + jc);
        const float4* bb4 = (const float4*)(bel + jc);
        float4 y0 = lnout(A0, m, inv, ((const float4*)(xr + jc))[0], gg4[0], bb4[0]);
        float4 y1 = lnout(A1, m, inv, ((const float4*)(xr + jc))[1], gg4[1], bb4[1]);
        float4 y2 = lnout(A2, m, inv, ((const float4*)(xr + jc))[2], gg4[2], bb4[2]);
        float4 y3 = lnout(A3, m, inv, ((const float4*)(xr + jc))[3], gg4[3], bb4[3]);
        float4* xw = (float4*)(xt + (size_t)n * 64 + jc);
        xw[0] = y0; xw[1] = y1; xw[2] = y2; xw[3] = y3;
        uint2* mt = (uint2*)(mo_t + (size_t)n * 64 + jc);
        mt[0] = make_uint2(PACK2(y0.x, y0.y), PACK2(y0.z, y0.w));
        mt[1] = make_uint2(PACK2(y1.x, y1.y), PACK2(y1.z, y1.w));
        mt[2] = make_uint2(PACK2(y2.x, y2.y), PACK2(y2.z, y2.w));
        mt[3] = make_uint2(PACK2(y3.x, y3.y), PACK2(y3.z, y3.w));
    }
}

// ---- generic fallback kernels (B != 2) ----
__global__ __launch_bounds__(256) void k_gather_struct_gen(
    const float* __restrict__ x, float* __restrict__ agg,
    const int* __restrict__ off, const int* __restrict__ packed,
    const float* __restrict__ rel, const int* __restrict__ h_index,
    int N, int BN)
{
    int wid = (blockIdx.x * 256 + threadIdx.x) >> 6;
    int lane = threadIdx.x & 63;
    if (wid >= BN) return;
    int b = wid / N;
    int n = wid - b * N;
    float r0 = rel[lane], r1 = rel[64 + lane];
    float r2 = rel[128 + lane], r3 = rel[192 + lane];
    const float* xb = x + (size_t)b * N * 64;
    float acc = (n == h_index[b]) ? 1.0f : 0.0f;
    int p0 = off[n], p1 = off[n + 1];
    for (int p = p0; p < p1; ++p) {
        int pk = packed[p];
        int s = pk & 0x03FFFFFF, ty = pk >> 27;
        acc = fmaf(xb[(size_t)s * 64 + lane], RSEL(ty), acc);
    }
    agg[(size_t)wid * 64 + lane] = acc;
}

__global__ __launch_bounds__(256) void k_update_gen(
    const float* __restrict__ W, const float* __restrict__ bias,
    const float* __restrict__ g, const float* __restrict__ beta,
    float* __restrict__ x, const float* __restrict__ agg, int rows)
{
    __shared__ float Wl[128 * 64];
    __shared__ float bl[64], gl[64], bel[64];
    int tid = threadIdx.x;
    {
        const float4* W4 = (const float4*)W;
        float4* Wl4 = (float4*)Wl;
        #pragma unroll
        for (int i = 0; i < 8; ++i) Wl4[tid + i * 256] = W4[tid + i * 256];
        if (tid < 64) { bl[tid] = bias[tid]; gl[tid] = g[tid]; bel[tid] = beta[tid]; }
    }
    __syncthreads();
    int gt2 = blockIdx.x * 256 + tid;
    int row = gt2 >> 2, q = gt2 & 3, jc = q * 16;
    if (row >= rows) return;
    const float* xr = x + (size_t)row * 64;
    const float* ar = agg + (size_t)row * 64;
    const float4* bj = (const float4*)(bl + jc);
    float4 A0 = bj[0], A1 = bj[1], A2 = bj[2], A3 = bj[3];
    #pragma unroll
    for (int kb = 0; kb < 64; kb += 4) {
        float4 iv = *(const float4*)(xr + kb);
        FMA4R(iv.x, Wl + (kb + 0) * 64 + jc, A0, A1, A2, A3);
        FMA4R(iv.y, Wl + (kb + 1) * 64 + jc, A0, A1, A2, A3);
        FMA4R(iv.z, Wl + (kb + 2) * 64 + jc, A0, A1, A2, A3);
        FMA4R(iv.w, Wl + (kb + 3) * 64 + jc, A0, A1, A2, A3);
    }
    #pragma unroll
    for (int kb = 0; kb < 64; kb += 4) {
        float4 iv = *(const float4*)(ar + kb);
        FMA4R(iv.x, Wl + (64 + kb + 0) * 64 + jc, A0, A1, A2, A3);
        FMA4R(iv.y, Wl + (64 + kb + 1) * 64 + jc, A0, A1, A2, A3);
        FMA4R(iv.z, Wl + (64 + kb + 2) * 64 + jc, A0, A1, A2, A3);
        FMA4R(iv.w, Wl + (64 + kb + 3) * 64 + jc, A0, A1, A2, A3);
    }
    float ls = SUM4(A0) + SUM4(A1) + SUM4(A2) + SUM4(A3);
    ls += __shfl_xor(ls, 1); ls += __shfl_xor(ls, 2);
    float m = ls * (1.0f / 64.0f);
    float vs = 0.f;
    VAR4M(A0, m, vs); VAR4M(A1, m, vs); VAR4M(A2, m, vs); VAR4M(A3, m, vs);
    vs += __shfl_xor(vs, 1); vs += __shfl_xor(vs, 2);
    float inv = rsqrtf(vs * (1.0f / 64.0f) + 1e-5f);
    const float4* gg4 = (const float4*)(gl + jc);
    const float4* bb4 = (const float4*)(bel + jc);
    float4 y0 = lnout(A0, m, inv, ((const float4*)(xr + jc))[0], gg4[0], bb4[0]);
    float4 y1 = lnout(A1, m, inv, ((const float4*)(xr + jc))[1], gg4[1], bb4[1]);
    float4 y2 = lnout(A2, m, inv, ((const float4*)(xr + jc))[2], gg4[2], bb4[2]);
    float4 y3 = lnout(A3, m, inv, ((const float4*)(xr + jc))[3], gg4[3], bb4[3]);
    float4* xw = (float4*)(x + (size_t)row * 64 + jc);
    xw[0] = y0; xw[1] = y1; xw[2] = y2; xw[3] = y3;
}

// ---- fusion: 4 threads/row, single-row (known-good) ----
__global__ __launch_bounds__(256) void k_fuse(
    const float* __restrict__ W1, const float* __restrict__ b1,
    const float* __restrict__ W2, const float* __restrict__ b2,
    float* __restrict__ out, const float* __restrict__ z, int N, int rows)
{
    __shared__ float W1l[128 * 64];
    __shared__ float W2l[64 * 64];
    __shared__ float b1l[64], b2l[64];
    int tid = threadIdx.x;
    {
        const float4* Wa = (const float4*)W1;
        float4* Wla = (float4*)W1l;
        #pragma unroll
        for (int i = 0; i < 8; ++i) Wla[tid + i * 256] = Wa[tid + i * 256];
        const float4* Wb = (const float4*)W2;
        float4* Wlb = (float4*)W2l;
        #pragma unroll
        for (int i = 0; i < 4; ++i) Wlb[tid + i * 256] = Wb[tid + i * 256];
        if (tid < 64) { b1l[tid] = b1[tid]; b2l[tid] = b2[tid]; }
    }
    __syncthreads();

    int gt2 = blockIdx.x * 256 + tid;
    int row = gt2 >> 2;
    int q = gt2 & 3;
    int jc = q * 16;
    if (row >= rows) return;
    int n = row % N;
    const float* hr = out + (size_t)row * 64;
    const float* zr = z + (size_t)n * 64;
    int lane = tid & 63;

    const float4* bj = (const float4*)(b1l + jc);
    float4 F0 = bj[0], F1 = bj[1], F2 = bj[2], F3 = bj[3];
    #pragma unroll
    for (int kb = 0; kb < 64; kb += 4) {
        float4 iv = *(const float4*)(hr + kb);
        FMA4R(iv.x, W1l + (kb + 0) * 64 + jc, F0, F1, F2, F3);
        FMA4R(iv.y, W1l + (kb + 1) * 64 + jc, F0, F1, F2, F3);
        FMA4R(iv.z, W1l + (kb + 2) * 64 + jc, F0, F1, F2, F3);
        FMA4R(iv.w, W1l + (kb + 3) * 64 + jc, F0, F1, F2, F3);
    }
    #pragma unroll
    for (int kb = 0; kb < 64; kb += 4) {
        float4 iv = *(const float4*)(zr + kb);
        FMA4R(iv.x, W1l + (64 + kb + 0) * 64 + jc, F0, F1, F2, F3);
        FMA4R(iv.y, W1l + (64 + kb + 1) * 64 + jc, F0, F1, F2, F3);
        FMA4R(iv.z, W1l + (64 + kb + 2) * 64 + jc, F0, F1, F2, F3);
        FMA4R(iv.w, W1l + (64 + kb + 3) * 64 + jc, F0, F1, F2, F3);
    }
    F0.x = fmaxf(F0.x, 0.f); F0.y = fmaxf(F0.y, 0.f); F0.z = fmaxf(F0.z, 0.f); F0.w = fmaxf(F0.w, 0.f);
    F1.x = fmaxf(F1.x, 0.f); F1.y = fmaxf(F1.y, 0.f); F1.z = fmaxf(F1.z, 0.f); F1.w = fmaxf(F1.w, 0.f);
    F2.x = fmaxf(F2.x, 0.f); F2.y = fmaxf(F2.y, 0.f); F2.z = fmaxf(F2.z, 0.f); F2.w = fmaxf(F2.w, 0.f);
    F3.x = fmaxf(F3.x, 0.f); F3.y = fmaxf(F3.y, 0.f); F3.z = fmaxf(F3.z, 0.f); F3.w = fmaxf(F3.w, 0.f);

    const float4* bj2 = (const float4*)(b2l + jc);
    float4 O0 = bj2[0], O1 = bj2[1], O2 = bj2[2], O3 = bj2[3];
    int srcLane = (lane & ~3) | ((q + 1) & 3);
    #pragma unroll
    for (int s = 0; s < 4; ++s) {
        int c = (q + s) & 3;
        const float* w2 = W2l + (c * 16) * 64 + jc;
        FMA4R(F0.x, w2 + 0 * 64,  O0, O1, O2, O3);
        FMA4R(F0.y, w2 + 1 * 64,  O0, O1, O2, O3);
        FMA4R(F0.z, w2 + 2 * 64,  O0, O1, O2, O3);
        FMA4R(F0.w, w2 + 3 * 64,  O0, O1, O2, O3);
        FMA4R(F1.x, w2 + 4 * 64,  O0, O1, O2, O3);
        FMA4R(F1.y, w2 + 5 * 64,  O0, O1, O2, O3);
        FMA4R(F1.z, w2 + 6 * 64,  O0, O1, O2, O3);
        FMA4R(F1.w, w2 + 7 * 64,  O0, O1, O2, O3);
        FMA4R(F2.x, w2 + 8 * 64,  O0, O1, O2, O3);
        FMA4R(F2.y, w2 + 9 * 64,  O0, O1, O2, O3);
        FMA4R(F2.z, w2 + 10 * 64, O0, O1, O2, O3);
        FMA4R(F2.w, w2 + 11 * 64, O0, O1, O2, O3);
        FMA4R(F3.x, w2 + 12 * 64, O0, O1, O2, O3);
        FMA4R(F3.y, w2 + 13 * 64, O0, O1, O2, O3);
        FMA4R(F3.z, w2 + 14 * 64, O0, O1, O2, O3);
        FMA4R(F3.w, w2 + 15 * 64, O0, O1, O2, O3);
        if (s < 3) {
            F0.x = __shfl(F0.x, srcLane); F0.y = __shfl(F0.y, srcLane);
            F0.z = __shfl(F0.z, srcLane); F0.w = __shfl(F0.w, srcLane);
            F1.x = __shfl(F1.x, srcLane); F1.y = __shfl(F1.y, srcLane);
            F1.z = __shfl(F1.z, srcLane); F1.w = __shfl(F1.w, srcLane);
            F2.x = __shfl(F2.x, srcLane); F2.y = __shfl(F2.y, srcLane);
            F2.z = __shfl(F2.z, srcLane); F2.w = __shfl(F2.w, srcLane);
            F3.x = __shfl(F3.x, srcLane); F3.y = __shfl(F3.y, srcLane);
            F3.z = __shfl(F3.z, srcLane); F3.w = __shfl(F3.w, srcLane);
        }
    }
    float4* ow4 = (float4*)(out + (size_t)row * 64 + jc);
    ow4[0] = O0; ow4[1] = O1; ow4[2] = O2; ow4[3] = O3;
}

extern "C" void kernel_launch(void* const* d_in, const int* in_sizes, int n_in,
                              void* d_out, int out_size, void* d_ws, size_t ws_size,
                              hipStream_t stream)
{
    const float* rel_text_init = (const float*)d_in[0];
    const float* struct_rel    = (const float*)d_in[1];
    const float* struct_W      = (const float*)d_in[2];
    const float* struct_b      = (const float*)d_in[3];
    const float* struct_g      = (const float*)d_in[4];
    const float* struct_beta   = (const float*)d_in[5];
    const float* text_rel      = (const float*)d_in[6];
    const float* text_W        = (const float*)d_in[7];
    const float* text_b        = (const float*)d_in[8];
    const float* text_g        = (const float*)d_in[9];
    const float* text_beta     = (const float*)d_in[10];
    const float* fuse_W1       = (const float*)d_in[11];
    const float* fuse_b1       = (const float*)d_in[12];
    const float* fuse_W2       = (const float*)d_in[13];
    const float* fuse_b2       = (const float*)d_in[14];
    const int*   h_index       = (const int*)d_in[15];
    const int*   edge_index    = (const int*)d_in[16];
    const int*   edge_type     = (const int*)d_in[17];
    const int*   text_edge_idx = (const int*)d_in[18];

    const int B  = in_sizes[15];
    const int N  = in_sizes[0] / 64;
    const int E  = in_sizes[17];
    const int ET = in_sizes[18] / 2;
    const int L  = in_sizes[3] / 64;
    const int R  = in_sizes[1] / (L * 64);

    const int* src  = edge_index;
    const int* dst  = edge_index + E;
    const int* tsrc = text_edge_idx;
    const int* tdst = text_edge_idx + ET;

    // ---- workspace layout ----
    float* x_t = (float*)d_ws;                          // [N,64] fp32 (in place)
    unsigned* mirA_s = (unsigned*)(x_t + (size_t)N * 64);   // [N,64] interleaved
    unsigned* mirB_s = mirA_s + (size_t)N * 64;
    unsigned short* mirA_t = (unsigned short*)(mirB_s + (size_t)N * 64); // [N,64]
    unsigned short* mirB_t = mirA_t + (size_t)N * 64;
    int* cnt_s = (int*)(mirB_t + (size_t)N * 64);       // [N]
    int* off_s = cnt_s + N;                             // [N+1]
    int* pk_s  = off_s + N + 1;                         // [E]
    int* cnt_t = pk_s + E;                              // [N]
    int* off_t = cnt_t + N;                             // [N+1]
    int* pk_t  = off_t + N + 1;                         // [ET]
    int* bsum_s = pk_t + ET;                            // [<=1024]
    int* bsum_t = bsum_s + 1024;                        // [<=1024]
    float* agg_gen = (float*)mirA_s;                    // B!=2 fallback only

    float* x_s = (float*)d_out;                         // [B,N,64] fp32 (in place)

    const size_t nd  = (size_t)N * 64;
    const int rows_s = B * N;
    const int tot_s  = rows_s * 64;
    const int nb     = (N + 1023) / 1024;
    const int b2     = (B == 2) ? 1 : 0;
    const int nlb    = (N + 63) / 64;

    const int gb_init  = (tot_s + 255) / 256;
    const int gb_castt = ((int)nd + 255) / 256;
    const int gb_hist  = (E + ET + 255) / 256;

    // ---- CSR builds ----
    hipMemsetAsync(cnt_s, 0, (size_t)N * 4, stream);
    hipMemsetAsync(cnt_t, 0, (size_t)N * 4, stream);
    k_hist_all<<<gb_hist, 256, 0, stream>>>(dst, tdst, cnt_s, cnt_t, E, ET);
    k_scan_blk2<<<2 * nb, 1024, 0, stream>>>(cnt_s, off_s, bsum_s,
                                             cnt_t, off_t, bsum_t, N, nb);
    k_scan_top2<<<2, 1024, 0, stream>>>(bsum_s, bsum_t, nb);
    k_scan_add2<<<2 * nb, 1024, 0, stream>>>(bsum_s, off_s, bsum_t, off_t, N, nb);
    k_fill_all<<<gb_hist, 256, 0, stream>>>(src, dst, edge_type, off_s, cnt_s, pk_s,
                                            tsrc, tdst, off_t, cnt_t, pk_t, E, ET);

    // ---- boundaries ----
    k_init_onehot<<<gb_init, 256, 0, stream>>>(x_s, mirA_s, h_index, N, tot_s, b2);
    k_cast_init<<<gb_castt, 256, 0, stream>>>(rel_text_init, x_t, mirA_t, (int)nd);

    // ---- 6 layers ----
    for (int i = 0; i < L; ++i) {
        const unsigned* mis = (i & 1) ? mirB_s : mirA_s;
        unsigned*       mos = (i & 1) ? mirA_s : mirB_s;
        const unsigned short* mit = (i & 1) ? mirB_t : mirA_t;
        unsigned short*       mot = (i & 1) ? mirA_t : mirB_t;
        if (b2) {
            k_layer_all<<<2 * nlb, 256, 0, stream>>>(
                mis, mos, x_s, off_s, pk_s,
                struct_rel + (size_t)i * R * 64, h_index,
                struct_W + (size_t)i * 128 * 64, struct_b + i * 64,
                struct_g + i * 64, struct_beta + i * 64,
                mit, mot, x_t, off_t, pk_t,
                text_rel + (size_t)i * 64, rel_text_init,
                text_W + (size_t)i * 128 * 64, text_b + i * 64,
                text_g + i * 64, text_beta + i * 64,
                N, nlb, nlb);
        } else {
            k_gather_struct_gen<<<(rows_s * 64 + 255) / 256, 256, 0, stream>>>(
                x_s, agg_gen, off_s, pk_s,
                struct_rel + (size_t)i * R * 64, h_index, N, rows_s);
            k_update_gen<<<(rows_s * 4 + 255) / 256, 256, 0, stream>>>(
                struct_W + (size_t)i * 128 * 64, struct_b + i * 64,
                struct_g + i * 64, struct_beta + i * 64, x_s, agg_gen, rows_s);
            k_layer_all<<<nlb, 256, 0, stream>>>(
                nullptr, nullptr, x_s, off_s, pk_s,
                struct_rel + (size_t)i * R * 64, h_index,
                struct_W + (size_t)i * 128 * 64, struct_b + i * 64,
                struct_g + i * 64, struct_beta + i * 64,
                mit, mot, x_t, off_t, pk_t,
                text_rel + (size_t)i * 64, rel_text_init,
                text_W + (size_t)i * 128 * 64, text_b + i * 64,
                text_g + i * 64, text_beta + i * 64,
                N, 0, nlb);
        }
    }

    // ---- fusion ----
    k_fuse<<<(rows_s * 4 + 255) / 256, 256, 0, stream>>>(
        fuse_W1, fuse_b1, fuse_W2, fuse_b2, x_s, x_t, N, rows_s);
}

// Round 14
// 692.607 us; speedup vs baseline: 2.7749x; 2.7749x over previous
//
#include <hip/hip_runtime.h>

// ---------------------------------------------------------------------------
// SemmaRelModel: two 6-layer NBFNet branches + MLP fusion.
// Round 14: REVERT to round-10 configuration (best measured: 693 us).
//   Round-13 post-mortem: fusing gather+update into one 66KB-LDS kernel cut
//   occupancy to 2 blocks/CU (9%) and starved the latency-bound gather of
//   TLP (3x slower). Rounds 11-12 (interleaved mirror) also net-regressed.
//   Round-10 structure: separate bf16 mirrors (struct [B*N,64], text [N,64]),
//   merged gather launch (struct+text block-interleaved), 2-row update,
//   single-row fuse.
// ---------------------------------------------------------------------------

__device__ __forceinline__ float bf2f(unsigned short u) {
    return __uint_as_float(((unsigned)u) << 16);
}
__device__ __forceinline__ unsigned short f2bf(float f) {
    unsigned u = __float_as_uint(f);
    u += 0x7FFF + ((u >> 16) & 1);          // round-to-nearest-even
    return (unsigned short)(u >> 16);
}
#define PACK2(a, b) ((unsigned)f2bf(a) | ((unsigned)f2bf(b) << 16))

#define FMA4R(v, wbase, R0, R1, R2, R3) do {                                  \
    const float4* _w = (const float4*)(wbase); float4 _t;                     \
    _t=_w[0]; R0.x=fmaf(v,_t.x,R0.x); R0.y=fmaf(v,_t.y,R0.y); R0.z=fmaf(v,_t.z,R0.z); R0.w=fmaf(v,_t.w,R0.w); \
    _t=_w[1]; R1.x=fmaf(v,_t.x,R1.x); R1.y=fmaf(v,_t.y,R1.y); R1.z=fmaf(v,_t.z,R1.z); R1.w=fmaf(v,_t.w,R1.w); \
    _t=_w[2]; R2.x=fmaf(v,_t.x,R2.x); R2.y=fmaf(v,_t.y,R2.y); R2.z=fmaf(v,_t.z,R2.z); R2.w=fmaf(v,_t.w,R2.w); \
    _t=_w[3]; R3.x=fmaf(v,_t.x,R3.x); R3.y=fmaf(v,_t.y,R3.y); R3.z=fmaf(v,_t.z,R3.z); R3.w=fmaf(v,_t.w,R3.w); \
} while (0)

#define FMA4R2(v0, v1, wbase, P0,P1,P2,P3, Q0,Q1,Q2,Q3) do {                  \
    const float4* _w = (const float4*)(wbase); float4 _t;                     \
    _t=_w[0];                                                                 \
    P0.x=fmaf(v0,_t.x,P0.x); P0.y=fmaf(v0,_t.y,P0.y); P0.z=fmaf(v0,_t.z,P0.z); P0.w=fmaf(v0,_t.w,P0.w); \
    Q0.x=fmaf(v1,_t.x,Q0.x); Q0.y=fmaf(v1,_t.y,Q0.y); Q0.z=fmaf(v1,_t.z,Q0.z); Q0.w=fmaf(v1,_t.w,Q0.w); \
    _t=_w[1];                                                                 \
    P1.x=fmaf(v0,_t.x,P1.x); P1.y=fmaf(v0,_t.y,P1.y); P1.z=fmaf(v0,_t.z,P1.z); P1.w=fmaf(v0,_t.w,P1.w); \
    Q1.x=fmaf(v1,_t.x,Q1.x); Q1.y=fmaf(v1,_t.y,Q1.y); Q1.z=fmaf(v1,_t.z,Q1.z); Q1.w=fmaf(v1,_t.w,Q1.w); \
    _t=_w[2];                                                                 \
    P2.x=fmaf(v0,_t.x,P2.x); P2.y=fmaf(v0,_t.y,P2.y); P2.z=fmaf(v0,_t.z,P2.z); P2.w=fmaf(v0,_t.w,P2.w); \
    Q2.x=fmaf(v1,_t.x,Q2.x); Q2.y=fmaf(v1,_t.y,Q2.y); Q2.z=fmaf(v1,_t.z,Q2.z); Q2.w=fmaf(v1,_t.w,Q2.w); \
    _t=_w[3];                                                                 \
    P3.x=fmaf(v0,_t.x,P3.x); P3.y=fmaf(v0,_t.y,P3.y); P3.z=fmaf(v0,_t.z,P3.z); P3.w=fmaf(v0,_t.w,P3.w); \
    Q3.x=fmaf(v1,_t.x,Q3.x); Q3.y=fmaf(v1,_t.y,Q3.y); Q3.z=fmaf(v1,_t.z,Q3.z); Q3.w=fmaf(v1,_t.w,Q3.w); \
} while (0)

#define SUM4(Ai) ((Ai.x + Ai.y) + (Ai.z + Ai.w))
#define VAR4M(Ai, mm, vv) do { float _c;                                      \
    _c = Ai.x - mm; vv = fmaf(_c, _c, vv); _c = Ai.y - mm; vv = fmaf(_c, _c, vv); \
    _c = Ai.z - mm; vv = fmaf(_c, _c, vv); _c = Ai.w - mm; vv = fmaf(_c, _c, vv); \
} while (0)

#define RSEL(ty) (((ty) < 2) ? ((ty) == 0 ? r0 : r1) : ((ty) == 2 ? r2 : r3))

__global__ __launch_bounds__(256) void k_init_onehot(
    float* __restrict__ x, unsigned short* __restrict__ xbf,
    const int* __restrict__ h_index, int N, int total)
{
    int idx = blockIdx.x * 256 + threadIdx.x;
    if (idx >= total) return;
    int row = idx >> 6;
    int b = row / N;
    int n = row - b * N;
    bool hit = (n == h_index[b]);
    x[idx] = hit ? 1.0f : 0.0f;
    xbf[idx] = hit ? 0x3F80 : 0;
}

__global__ __launch_bounds__(256) void k_cast_init(
    const float* __restrict__ init, float* __restrict__ x,
    unsigned short* __restrict__ xbf, int total)
{
    int idx = blockIdx.x * 256 + threadIdx.x;
    if (idx >= total) return;
    float f = init[idx];
    x[idx] = f;
    xbf[idx] = f2bf(f);
}

// ---- CSR build (both graphs per launch) ----
__global__ __launch_bounds__(256) void k_hist_all(
    const int* __restrict__ dst_s, const int* __restrict__ dst_t,
    int* __restrict__ cnt_s, int* __restrict__ cnt_t, int E, int ET)
{
    int i = blockIdx.x * 256 + threadIdx.x;
    if (i < E) atomicAdd(&cnt_s[dst_s[i]], 1);
    else if (i < E + ET) atomicAdd(&cnt_t[dst_t[i - E]], 1);
}

__global__ __launch_bounds__(1024) void k_scan_blk2(
    const int* __restrict__ cnt_s, int* __restrict__ off_s, int* __restrict__ bsum_s,
    const int* __restrict__ cnt_t, int* __restrict__ off_t, int* __restrict__ bsum_t,
    int n, int nb)
{
    bool tpath = blockIdx.x >= nb;
    int lb = tpath ? blockIdx.x - nb : blockIdx.x;
    const int* cnt = tpath ? cnt_t : cnt_s;
    int* off = tpath ? off_t : off_s;
    int* bsum = tpath ? bsum_t : bsum_s;

    __shared__ int wsum[16], wpre[16], tot;
    int tid = threadIdx.x, lane = tid & 63, w = tid >> 6;
    int i = lb * 1024 + tid;
    int v = (i < n) ? cnt[i] : 0;
    int s = v;
    #pragma unroll
    for (int d = 1; d < 64; d <<= 1) {
        int t = __shfl_up(s, d);
        if (lane >= d) s += t;
    }
    if (lane == 63) wsum[w] = s;
    __syncthreads();
    if (w == 0 && lane < 16) {
        int ws = wsum[lane];
        int p = ws;
        #pragma unroll
        for (int d = 1; d < 16; d <<= 1) {
            int t = __shfl_up(p, d);
            if (lane >= d) p += t;
        }
        wpre[lane] = p - ws;
        if (lane == 15) tot = p;
    }
    __syncthreads();
    if (i < n) off[i + 1] = wpre[w] + s;
    if (tid == 0) {
        bsum[lb] = tot;
        if (lb == 0) off[0] = 0;
    }
}

__global__ __launch_bounds__(1024) void k_scan_top2(
    int* __restrict__ bsum_s, int* __restrict__ bsum_t, int nb)
{
    int* bsum = (blockIdx.x == 0) ? bsum_s : bsum_t;
    __shared__ int wsum[16], wpre[16];
    int tid = threadIdx.x, lane = tid & 63, w = tid >> 6;
    int v = (tid < nb) ? bsum[tid] : 0;
    int s = v;
    #pragma unroll
    for (int d = 1; d < 64; d <<= 1) {
        int t = __shfl_up(s, d);
        if (lane >= d) s += t;
    }
    if (lane == 63) wsum[w] = s;
    __syncthreads();
    if (w == 0 && lane < 16) {
        int ws = wsum[lane];
        int p = ws;
        #pragma unroll
        for (int d = 1; d < 16; d <<= 1) {
            int t = __shfl_up(p, d);
            if (lane >= d) p += t;
        }
        wpre[lane] = p - ws;
    }
    __syncthreads();
    if (tid < nb) bsum[tid] = wpre[w] + s - v;
}

__global__ __launch_bounds__(1024) void k_scan_add2(
    const int* __restrict__ bsum_s, int* __restrict__ off_s,
    const int* __restrict__ bsum_t, int* __restrict__ off_t, int n, int nb)
{
    bool tpath = blockIdx.x >= nb;
    int lb = tpath ? blockIdx.x - nb : blockIdx.x;
    int i = lb * 1024 + threadIdx.x;
    if (i < n) (tpath ? off_t : off_s)[i + 1] += (tpath ? bsum_t : bsum_s)[lb];
}

__global__ __launch_bounds__(256) void k_fill_all(
    const int* __restrict__ src_s, const int* __restrict__ dst_s,
    const int* __restrict__ etype,
    const int* __restrict__ off_s, int* __restrict__ cnt_s, int* __restrict__ pk_s,
    const int* __restrict__ src_t, const int* __restrict__ dst_t,
    const int* __restrict__ off_t, int* __restrict__ cnt_t, int* __restrict__ pk_t,
    int E, int ET)
{
    int i = blockIdx.x * 256 + threadIdx.x;
    if (i < E) {
        int d = dst_s[i];
        int pos = off_s[d] + atomicSub(&cnt_s[d], 1) - 1;
        pk_s[pos] = src_s[i] | (etype[i] << 27);
    } else if (i < E + ET) {
        int e = i - E;
        int d = dst_t[e];
        int pos = off_t[d] + atomicSub(&cnt_t[d], 1) - 1;
        pk_t[pos] = src_t[e];
    }
}

// ---- combined aggregation: struct (both batches) + text; bf16 row reads ----
__global__ __launch_bounds__(256) void k_gather_all(
    const unsigned short* __restrict__ xbs, float* __restrict__ aggs,
    const int* __restrict__ offs, const int* __restrict__ pks,
    const float* __restrict__ rels,      // [4,64]
    const int* __restrict__ hidx,
    const unsigned short* __restrict__ xbt, float* __restrict__ aggt,
    const int* __restrict__ offt, const int* __restrict__ pkt,
    const float* __restrict__ relt,      // [64]
    const float* __restrict__ init,      // [N,64]
    int N, int sblocks, int tblocks)
{
    int tid = threadIdx.x;
    int lane = tid & 63;
    bool isStruct; int lb;
    if (sblocks == tblocks) { isStruct = !(blockIdx.x & 1); lb = blockIdx.x >> 1; }
    else if ((int)blockIdx.x < sblocks) { isStruct = true; lb = blockIdx.x; }
    else { isStruct = false; lb = blockIdx.x - sblocks; }
    int n = (lb * 256 + tid) >> 6;
    if (n >= N) return;

    if (isStruct) {
        float r0 = rels[lane], r1 = rels[64 + lane];
        float r2 = rels[128 + lane], r3 = rels[192 + lane];
        const unsigned short* x0 = xbs;
        const unsigned short* x1 = xbs + (size_t)N * 64;
        float acc0 = (n == hidx[0]) ? 1.0f : 0.0f;
        float acc1 = (n == hidx[1]) ? 1.0f : 0.0f;
        int p0 = __builtin_amdgcn_readfirstlane(offs[n]);
        int p1 = __builtin_amdgcn_readfirstlane(offs[n + 1]);
        for (int p = p0; p < p1; p += 64) {
            int myPk = (p + lane < p1) ? pks[p + lane] : 0;
            int cnt = min(p1 - p, 64);
            int i = 0;
            for (; i + 4 <= cnt; i += 4) {
                int pka = __shfl(myPk, i + 0), pkb = __shfl(myPk, i + 1);
                int pkc = __shfl(myPk, i + 2), pkd = __shfl(myPk, i + 3);
                int sa = pka & 0x03FFFFFF, ta = pka >> 27;
                int sb = pkb & 0x03FFFFFF, tb = pkb >> 27;
                int sc = pkc & 0x03FFFFFF, tc = pkc >> 27;
                int sd = pkd & 0x03FFFFFF, td = pkd >> 27;
                float ra = RSEL(ta), rb = RSEL(tb), rc = RSEL(tc), rd = RSEL(td);
                float a0 = bf2f(x0[(size_t)sa * 64 + lane]), a1 = bf2f(x1[(size_t)sa * 64 + lane]);
                float b0 = bf2f(x0[(size_t)sb * 64 + lane]), b1 = bf2f(x1[(size_t)sb * 64 + lane]);
                float c0 = bf2f(x0[(size_t)sc * 64 + lane]), c1 = bf2f(x1[(size_t)sc * 64 + lane]);
                float d0 = bf2f(x0[(size_t)sd * 64 + lane]), d1 = bf2f(x1[(size_t)sd * 64 + lane]);
                acc0 = fmaf(a0, ra, acc0); acc1 = fmaf(a1, ra, acc1);
                acc0 = fmaf(b0, rb, acc0); acc1 = fmaf(b1, rb, acc1);
                acc0 = fmaf(c0, rc, acc0); acc1 = fmaf(c1, rc, acc1);
                acc0 = fmaf(d0, rd, acc0); acc1 = fmaf(d1, rd, acc1);
            }
            for (; i < cnt; ++i) {
                int pk = __shfl(myPk, i);
                int s = pk & 0x03FFFFFF, ty = pk >> 27;
                float r = RSEL(ty);
                acc0 = fmaf(bf2f(x0[(size_t)s * 64 + lane]), r, acc0);
                acc1 = fmaf(bf2f(x1[(size_t)s * 64 + lane]), r, acc1);
            }
        }
        aggs[(size_t)n * 64 + lane] = acc0;
        aggs[(size_t)(N + n) * 64 + lane] = acc1;
    } else {
        float r = relt[lane];
        float acc = init[(size_t)n * 64 + lane];
        float acc2 = 0.f;
        int p0 = __builtin_amdgcn_readfirstlane(offt[n]);
        int p1 = __builtin_amdgcn_readfirstlane(offt[n + 1]);
        for (int p = p0; p < p1; p += 64) {
            int myPk = (p + lane < p1) ? pkt[p + lane] : 0;
            int cnt = min(p1 - p, 64);
            int i = 0;
            for (; i + 8 <= cnt; i += 8) {
                int s0 = __shfl(myPk, i + 0), s1 = __shfl(myPk, i + 1);
                int s2 = __shfl(myPk, i + 2), s3 = __shfl(myPk, i + 3);
                int s4 = __shfl(myPk, i + 4), s5 = __shfl(myPk, i + 5);
                int s6 = __shfl(myPk, i + 6), s7 = __shfl(myPk, i + 7);
                float a = bf2f(xbt[(size_t)s0 * 64 + lane]), b = bf2f(xbt[(size_t)s1 * 64 + lane]);
                float c = bf2f(xbt[(size_t)s2 * 64 + lane]), d = bf2f(xbt[(size_t)s3 * 64 + lane]);
                float e = bf2f(xbt[(size_t)s4 * 64 + lane]), f = bf2f(xbt[(size_t)s5 * 64 + lane]);
                float g = bf2f(xbt[(size_t)s6 * 64 + lane]), h = bf2f(xbt[(size_t)s7 * 64 + lane]);
                acc = fmaf(a, r, acc);  acc2 = fmaf(b, r, acc2);
                acc = fmaf(c, r, acc);  acc2 = fmaf(d, r, acc2);
                acc = fmaf(e, r, acc);  acc2 = fmaf(f, r, acc2);
                acc = fmaf(g, r, acc);  acc2 = fmaf(h, r, acc2);
            }
            for (; i < cnt; ++i) {
                int s = __shfl(myPk, i);
                acc = fmaf(bf2f(xbt[(size_t)s * 64 + lane]), r, acc);
            }
        }
        aggt[(size_t)n * 64 + lane] = acc + acc2;
    }
}

// generic fallback (B != 2): fp32 reads, correctness path
__global__ __launch_bounds__(256) void k_gather_struct_gen(
    const float* __restrict__ x, float* __restrict__ agg,
    const int* __restrict__ off, const int* __restrict__ packed,
    const float* __restrict__ rel, const int* __restrict__ h_index,
    int N, int BN)
{
    int wid = (blockIdx.x * 256 + threadIdx.x) >> 6;
    int lane = threadIdx.x & 63;
    if (wid >= BN) return;
    int b = wid / N;
    int n = wid - b * N;
    float r0 = rel[lane], r1 = rel[64 + lane];
    float r2 = rel[128 + lane], r3 = rel[192 + lane];
    const float* xb = x + (size_t)b * N * 64;
    float acc = (n == h_index[b]) ? 1.0f : 0.0f;
    int p0 = off[n], p1 = off[n + 1];
    for (int p = p0; p < p1; ++p) {
        int pk = packed[p];
        int s = pk & 0x03FFFFFF, ty = pk >> 27;
        acc = fmaf(xb[(size_t)s * 64 + lane], RSEL(ty), acc);
    }
    agg[(size_t)wid * 64 + lane] = acc;
}

// ---- combined dense update: 4 threads/row, 2-row blocking; writes bf16 mirror
__global__ __launch_bounds__(256) void k_update_all(
    const float* __restrict__ Ws, const float* __restrict__ bs_,
    const float* __restrict__ gs, const float* __restrict__ betas,
    float* __restrict__ xs, unsigned short* __restrict__ xbs,
    const float* __restrict__ aggs, int rows_s,
    const float* __restrict__ Wt, const float* __restrict__ bt_,
    const float* __restrict__ gt_, const float* __restrict__ betat,
    float* __restrict__ xt, unsigned short* __restrict__ xbt,
    const float* __restrict__ aggt, int rows_t,
    int bs_blocks, int bt_blocks)
{
    bool tpath; int lb;
    if (bs_blocks == 2 * bt_blocks) {
        int m3 = blockIdx.x % 3, d3 = blockIdx.x / 3;
        if (m3 != 2) { tpath = false; lb = d3 * 2 + m3; }
        else { tpath = true; lb = d3; }
    } else if ((int)blockIdx.x < bs_blocks) { tpath = false; lb = blockIdx.x; }
    else { tpath = true; lb = blockIdx.x - bs_blocks; }

    const float* W    = tpath ? Wt : Ws;
    const float* bias = tpath ? bt_ : bs_;
    const float* g    = tpath ? gt_ : gs;
    const float* beta = tpath ? betat : betas;
    float* x          = tpath ? xt : xs;
    unsigned short* xb = tpath ? xbt : xbs;
    const float* agg  = tpath ? aggt : aggs;
    int rows          = tpath ? rows_t : rows_s;

    __shared__ float Wl[128 * 64];
    __shared__ float bl[64], gl[64], bel[64];
    int tid = threadIdx.x;
    {
        const float4* W4 = (const float4*)W;
        float4* Wl4 = (float4*)Wl;
        #pragma unroll
        for (int i = 0; i < 8; ++i) Wl4[tid + i * 256] = W4[tid + i * 256];
        if (tid < 64) { bl[tid] = bias[tid]; gl[tid] = g[tid]; bel[tid] = beta[tid]; }
    }
    __syncthreads();

    int gt2 = lb * 256 + tid;
    int pair = gt2 >> 2;
    int q = gt2 & 3, jc = q * 16;
    int r0i = pair * 2, r1i = r0i + 1;
    if (r0i >= rows) return;
    bool h1 = (r1i < rows);
    const float* xr0 = x + (size_t)r0i * 64;
    const float* ar0 = agg + (size_t)r0i * 64;
    const float* xr1 = h1 ? x + (size_t)r1i * 64 : xr0;
    const float* ar1 = h1 ? agg + (size_t)r1i * 64 : ar0;

    const float4* bj = (const float4*)(bl + jc);
    float4 A0 = bj[0], A1 = bj[1], A2 = bj[2], A3 = bj[3];
    float4 B0 = bj[0], B1 = bj[1], B2 = bj[2], B3 = bj[3];

    #pragma unroll
    for (int kb = 0; kb < 64; kb += 4) {
        float4 i0 = *(const float4*)(xr0 + kb);
        float4 i1 = *(const float4*)(xr1 + kb);
        FMA4R2(i0.x, i1.x, Wl + (kb + 0) * 64 + jc, A0,A1,A2,A3, B0,B1,B2,B3);
        FMA4R2(i0.y, i1.y, Wl + (kb + 1) * 64 + jc, A0,A1,A2,A3, B0,B1,B2,B3);
        FMA4R2(i0.z, i1.z, Wl + (kb + 2) * 64 + jc, A0,A1,A2,A3, B0,B1,B2,B3);
        FMA4R2(i0.w, i1.w, Wl + (kb + 3) * 64 + jc, A0,A1,A2,A3, B0,B1,B2,B3);
    }
    #pragma unroll
    for (int kb = 0; kb < 64; kb += 4) {
        float4 i0 = *(const float4*)(ar0 + kb);
        float4 i1 = *(const float4*)(ar1 + kb);
        FMA4R2(i0.x, i1.x, Wl + (64 + kb + 0) * 64 + jc, A0,A1,A2,A3, B0,B1,B2,B3);
        FMA4R2(i0.y, i1.y, Wl + (64 + kb + 1) * 64 + jc, A0,A1,A2,A3, B0,B1,B2,B3);
        FMA4R2(i0.z, i1.z, Wl + (64 + kb + 2) * 64 + jc, A0,A1,A2,A3, B0,B1,B2,B3);
        FMA4R2(i0.w, i1.w, Wl + (64 + kb + 3) * 64 + jc, A0,A1,A2,A3, B0,B1,B2,B3);
    }

    float ls0 = SUM4(A0) + SUM4(A1) + SUM4(A2) + SUM4(A3);
    float ls1 = SUM4(B0) + SUM4(B1) + SUM4(B2) + SUM4(B3);
    ls0 += __shfl_xor(ls0, 1); ls0 += __shfl_xor(ls0, 2);
    ls1 += __shfl_xor(ls1, 1); ls1 += __shfl_xor(ls1, 2);
    float m0 = ls0 * (1.0f / 64.0f), m1 = ls1 * (1.0f / 64.0f);
    float v0 = 0.f, v1 = 0.f;
    VAR4M(A0, m0, v0); VAR4M(A1, m0, v0); VAR4M(A2, m0, v0); VAR4M(A3, m0, v0);
    VAR4M(B0, m1, v1); VAR4M(B1, m1, v1); VAR4M(B2, m1, v1); VAR4M(B3, m1, v1);
    v0 += __shfl_xor(v0, 1); v0 += __shfl_xor(v0, 2);
    v1 += __shfl_xor(v1, 1); v1 += __shfl_xor(v1, 2);
    float inv0 = rsqrtf(v0 * (1.0f / 64.0f) + 1e-5f);
    float inv1 = rsqrtf(v1 * (1.0f / 64.0f) + 1e-5f);

    const float4* gg4 = (const float4*)(gl + jc);
    const float4* bb4 = (const float4*)(bel + jc);
    #define OUTC(Aj, c, mm, iv, xrp, xwp, xbm) do {                           \
        float4 xv = ((const float4*)(xrp))[c];                                \
        float4 gg = gg4[c]; float4 bb = bb4[c];                               \
        float4 y;                                                             \
        y.x = fmaxf((Aj.x - mm) * iv * gg.x + bb.x, 0.f) + xv.x;              \
        y.y = fmaxf((Aj.y - mm) * iv * gg.y + bb.y, 0.f) + xv.y;              \
        y.z = fmaxf((Aj.z - mm) * iv * gg.z + bb.z, 0.f) + xv.z;              \
        y.w = fmaxf((Aj.w - mm) * iv * gg.w + bb.w, 0.f) + xv.w;              \
        ((float4*)(xwp))[c] = y;                                              \
        ((uint2*)(xbm))[c] = make_uint2(PACK2(y.x, y.y), PACK2(y.z, y.w));    \
    } while (0)
    float* xw0 = x + (size_t)r0i * 64 + jc;
    unsigned short* xb0 = xb + (size_t)r0i * 64 + jc;
    OUTC(A0, 0, m0, inv0, xr0 + jc, xw0, xb0); OUTC(A1, 1, m0, inv0, xr0 + jc, xw0, xb0);
    OUTC(A2, 2, m0, inv0, xr0 + jc, xw0, xb0); OUTC(A3, 3, m0, inv0, xr0 + jc, xw0, xb0);
    if (h1) {
        float* xw1 = x + (size_t)r1i * 64 + jc;
        unsigned short* xb1 = xb + (size_t)r1i * 64 + jc;
        OUTC(B0, 0, m1, inv1, xr1 + jc, xw1, xb1); OUTC(B1, 1, m1, inv1, xr1 + jc, xw1, xb1);
        OUTC(B2, 2, m1, inv1, xr1 + jc, xw1, xb1); OUTC(B3, 3, m1, inv1, xr1 + jc, xw1, xb1);
    }
    #undef OUTC
}

// ---- fusion: 4 threads/row, single-row (round-7 known-good) ----
__global__ __launch_bounds__(256) void k_fuse(
    const float* __restrict__ W1, const float* __restrict__ b1,
    const float* __restrict__ W2, const float* __restrict__ b2,
    float* __restrict__ out, const float* __restrict__ z, int N, int rows)
{
    __shared__ float W1l[128 * 64];
    __shared__ float W2l[64 * 64];
    __shared__ float b1l[64], b2l[64];
    int tid = threadIdx.x;
    {
        const float4* Wa = (const float4*)W1;
        float4* Wla = (float4*)W1l;
        #pragma unroll
        for (int i = 0; i < 8; ++i) Wla[tid + i * 256] = Wa[tid + i * 256];
        const float4* Wb = (const float4*)W2;
        float4* Wlb = (float4*)W2l;
        #pragma unroll
        for (int i = 0; i < 4; ++i) Wlb[tid + i * 256] = Wb[tid + i * 256];
        if (tid < 64) { b1l[tid] = b1[tid]; b2l[tid] = b2[tid]; }
    }
    __syncthreads();

    int gt2 = blockIdx.x * 256 + tid;
    int row = gt2 >> 2;
    int q = gt2 & 3;
    int jc = q * 16;
    if (row >= rows) return;
    int n = row % N;
    const float* hr = out + (size_t)row * 64;
    const float* zr = z + (size_t)n * 64;
    int lane = tid & 63;

    const float4* bj = (const float4*)(b1l + jc);
    float4 F0 = bj[0], F1 = bj[1], F2 = bj[2], F3 = bj[3];
    #pragma unroll
    for (int kb = 0; kb < 64; kb += 4) {
        float4 iv = *(const float4*)(hr + kb);
        FMA4R(iv.x, W1l + (kb + 0) * 64 + jc, F0, F1, F2, F3);
        FMA4R(iv.y, W1l + (kb + 1) * 64 + jc, F0, F1, F2, F3);
        FMA4R(iv.z, W1l + (kb + 2) * 64 + jc, F0, F1, F2, F3);
        FMA4R(iv.w, W1l + (kb + 3) * 64 + jc, F0, F1, F2, F3);
    }
    #pragma unroll
    for (int kb = 0; kb < 64; kb += 4) {
        float4 iv = *(const float4*)(zr + kb);
        FMA4R(iv.x, W1l + (64 + kb + 0) * 64 + jc, F0, F1, F2, F3);
        FMA4R(iv.y, W1l + (64 + kb + 1) * 64 + jc, F0, F1, F2, F3);
        FMA4R(iv.z, W1l + (64 + kb + 2) * 64 + jc, F0, F1, F2, F3);
        FMA4R(iv.w, W1l + (64 + kb + 3) * 64 + jc, F0, F1, F2, F3);
    }
    F0.x = fmaxf(F0.x, 0.f); F0.y = fmaxf(F0.y, 0.f); F0.z = fmaxf(F0.z, 0.f); F0.w = fmaxf(F0.w, 0.f);
    F1.x = fmaxf(F1.x, 0.f); F1.y = fmaxf(F1.y, 0.f); F1.z = fmaxf(F1.z, 0.f); F1.w = fmaxf(F1.w, 0.f);
    F2.x = fmaxf(F2.x, 0.f); F2.y = fmaxf(F2.y, 0.f); F2.z = fmaxf(F2.z, 0.f); F2.w = fmaxf(F2.w, 0.f);
    F3.x = fmaxf(F3.x, 0.f); F3.y = fmaxf(F3.y, 0.f); F3.z = fmaxf(F3.z, 0.f); F3.w = fmaxf(F3.w, 0.f);

    const float4* bj2 = (const float4*)(b2l + jc);
    float4 O0 = bj2[0], O1 = bj2[1], O2 = bj2[2], O3 = bj2[3];
    int srcLane = (lane & ~3) | ((q + 1) & 3);
    #pragma unroll
    for (int s = 0; s < 4; ++s) {
        int c = (q + s) & 3;
        const float* w2 = W2l + (c * 16) * 64 + jc;
        FMA4R(F0.x, w2 + 0 * 64,  O0, O1, O2, O3);
        FMA4R(F0.y, w2 + 1 * 64,  O0, O1, O2, O3);
        FMA4R(F0.z, w2 + 2 * 64,  O0, O1, O2, O3);
        FMA4R(F0.w, w2 + 3 * 64,  O0, O1, O2, O3);
        FMA4R(F1.x, w2 + 4 * 64,  O0, O1, O2, O3);
        FMA4R(F1.y, w2 + 5 * 64,  O0, O1, O2, O3);
        FMA4R(F1.z, w2 + 6 * 64,  O0, O1, O2, O3);
        FMA4R(F1.w, w2 + 7 * 64,  O0, O1, O2, O3);
        FMA4R(F2.x, w2 + 8 * 64,  O0, O1, O2, O3);
        FMA4R(F2.y, w2 + 9 * 64,  O0, O1, O2, O3);
        FMA4R(F2.z, w2 + 10 * 64, O0, O1, O2, O3);
        FMA4R(F2.w, w2 + 11 * 64, O0, O1, O2, O3);
        FMA4R(F3.x, w2 + 12 * 64, O0, O1, O2, O3);
        FMA4R(F3.y, w2 + 13 * 64, O0, O1, O2, O3);
        FMA4R(F3.z, w2 + 14 * 64, O0, O1, O2, O3);
        FMA4R(F3.w, w2 + 15 * 64, O0, O1, O2, O3);
        if (s < 3) {
            F0.x = __shfl(F0.x, srcLane); F0.y = __shfl(F0.y, srcLane);
            F0.z = __shfl(F0.z, srcLane); F0.w = __shfl(F0.w, srcLane);
            F1.x = __shfl(F1.x, srcLane); F1.y = __shfl(F1.y, srcLane);
            F1.z = __shfl(F1.z, srcLane); F1.w = __shfl(F1.w, srcLane);
            F2.x = __shfl(F2.x, srcLane); F2.y = __shfl(F2.y, srcLane);
            F2.z = __shfl(F2.z, srcLane); F2.w = __shfl(F2.w, srcLane);
            F3.x = __shfl(F3.x, srcLane); F3.y = __shfl(F3.y, srcLane);
            F3.z = __shfl(F3.z, srcLane); F3.w = __shfl(F3.w, srcLane);
        }
    }
    float4* ow4 = (float4*)(out + (size_t)row * 64 + jc);
    ow4[0] = O0; ow4[1] = O1; ow4[2] = O2; ow4[3] = O3;
}

extern "C" void kernel_launch(void* const* d_in, const int* in_sizes, int n_in,
                              void* d_out, int out_size, void* d_ws, size_t ws_size,
                              hipStream_t stream)
{
    const float* rel_text_init = (const float*)d_in[0];
    const float* struct_rel    = (const float*)d_in[1];
    const float* struct_W      = (const float*)d_in[2];
    const float* struct_b      = (const float*)d_in[3];
    const float* struct_g      = (const float*)d_in[4];
    const float* struct_beta   = (const float*)d_in[5];
    const float* text_rel      = (const float*)d_in[6];
    const float* text_W        = (const float*)d_in[7];
    const float* text_b        = (const float*)d_in[8];
    const float* text_g        = (const float*)d_in[9];
    const float* text_beta     = (const float*)d_in[10];
    const float* fuse_W1       = (const float*)d_in[11];
    const float* fuse_b1       = (const float*)d_in[12];
    const float* fuse_W2       = (const float*)d_in[13];
    const float* fuse_b2       = (const float*)d_in[14];
    const int*   h_index       = (const int*)d_in[15];
    const int*   edge_index    = (const int*)d_in[16];
    const int*   edge_type     = (const int*)d_in[17];
    const int*   text_edge_idx = (const int*)d_in[18];

    const int B  = in_sizes[15];
    const int N  = in_sizes[0] / 64;
    const int E  = in_sizes[17];
    const int ET = in_sizes[18] / 2;
    const int L  = in_sizes[3] / 64;
    const int R  = in_sizes[1] / (L * 64);

    const int* src  = edge_index;
    const int* dst  = edge_index + E;
    const int* tsrc = text_edge_idx;
    const int* tdst = text_edge_idx + ET;

    // ---- workspace layout ----
    float* x_t   = (float*)d_ws;                        // [N,64]
    float* agg_t = x_t + (size_t)N * 64;                // [N,64]
    float* agg_s = agg_t + (size_t)N * 64;              // [B,N,64]
    unsigned short* xbf_s = (unsigned short*)(agg_s + (size_t)B * N * 64); // [B*N,64]
    unsigned short* xbf_t = xbf_s + (size_t)B * N * 64; // [N,64]
    int*   cnt_s = (int*)(xbf_t + (size_t)N * 64);      // [N]
    int*   off_s = cnt_s + N;                           // [N+1]
    int*   pk_s  = off_s + N + 1;                       // [E]
    int*   cnt_t = pk_s + E;                            // [N]
    int*   off_t = cnt_t + N;                           // [N+1]
    int*   pk_t  = off_t + N + 1;                       // [ET]
    int*   bsum_s = pk_t + ET;                          // [<=1024]
    int*   bsum_t = bsum_s + 1024;                      // [<=1024]

    float* x_s = (float*)d_out;                         // [B,N,64]

    const size_t nd  = (size_t)N * 64;
    const int rows_s = B * N;
    const int tot_s  = rows_s * 64;
    const int nb     = (N + 1023) / 1024;

    const int gb_init   = (tot_s + 255) / 256;
    const int gb_castt  = ((int)nd + 255) / 256;
    const int gb_hist   = (E + ET + 255) / 256;
    const int gb_wave_n = (N * 64 + 255) / 256;
    const int pairs_s   = (rows_s + 1) / 2;
    const int pairs_t   = (N + 1) / 2;
    const int bs_blocks = (pairs_s * 4 + 255) / 256;
    const int bt_blocks = (pairs_t * 4 + 255) / 256;
    const int gb_fuse   = (rows_s * 4 + 255) / 256;

    // ---- CSR builds ----
    hipMemsetAsync(cnt_s, 0, (size_t)N * 4, stream);
    hipMemsetAsync(cnt_t, 0, (size_t)N * 4, stream);
    k_hist_all<<<gb_hist, 256, 0, stream>>>(dst, tdst, cnt_s, cnt_t, E, ET);
    k_scan_blk2<<<2 * nb, 1024, 0, stream>>>(cnt_s, off_s, bsum_s,
                                             cnt_t, off_t, bsum_t, N, nb);
    k_scan_top2<<<2, 1024, 0, stream>>>(bsum_s, bsum_t, nb);
    k_scan_add2<<<2 * nb, 1024, 0, stream>>>(bsum_s, off_s, bsum_t, off_t, N, nb);
    k_fill_all<<<gb_hist, 256, 0, stream>>>(src, dst, edge_type, off_s, cnt_s, pk_s,
                                            tsrc, tdst, off_t, cnt_t, pk_t, E, ET);

    // ---- boundaries ----
    k_init_onehot<<<gb_init, 256, 0, stream>>>(x_s, xbf_s, h_index, N, tot_s);
    k_cast_init<<<gb_castt, 256, 0, stream>>>(rel_text_init, x_t, xbf_t, (int)nd);

    // ---- 6 layers, both branches per launch ----
    for (int i = 0; i < L; ++i) {
        if (B == 2) {
            k_gather_all<<<2 * gb_wave_n, 256, 0, stream>>>(
                xbf_s, agg_s, off_s, pk_s, struct_rel + (size_t)i * R * 64, h_index,
                xbf_t, agg_t, off_t, pk_t, text_rel + (size_t)i * 64, rel_text_init,
                N, gb_wave_n, gb_wave_n);
        } else {
            k_gather_struct_gen<<<(rows_s * 64 + 255) / 256, 256, 0, stream>>>(
                x_s, agg_s, off_s, pk_s,
                struct_rel + (size_t)i * R * 64, h_index, N, rows_s);
            k_gather_all<<<gb_wave_n, 256, 0, stream>>>(
                xbf_s, agg_s, off_s, pk_s, struct_rel + (size_t)i * R * 64, h_index,
                xbf_t, agg_t, off_t, pk_t, text_rel + (size_t)i * 64, rel_text_init,
                N, 0, gb_wave_n);
        }
        k_update_all<<<bs_blocks + bt_blocks, 256, 0, stream>>>(
            struct_W + (size_t)i * 128 * 64, struct_b + i * 64,
            struct_g + i * 64, struct_beta + i * 64, x_s, xbf_s, agg_s, rows_s,
            text_W + (size_t)i * 128 * 64, text_b + i * 64,
            text_g + i * 64, text_beta + i * 64, x_t, xbf_t, agg_t, N,
            bs_blocks, bt_blocks);
    }

    // ---- fusion ----
    k_fuse<<<gb_fuse, 256, 0, stream>>>(
        fuse_W1, fuse_b1, fuse_W2, fuse_b2, x_s, x_t, N, rows_s);
}